// Round 11
// baseline (185.606 us; speedup 1.0000x reference)
//
#include <hip/hip_runtime.h>
#include <stdint.h>
#include <stddef.h>

#define Bb 8
#define Cc 128
#define Hh 96
#define Ww 160
#define HW (Hh*Ww)         // 15360
#define Kk 81

typedef __attribute__((ext_vector_type(8))) short short8;
typedef __attribute__((ext_vector_type(4))) float floatx4;
typedef __attribute__((ext_vector_type(4))) unsigned int uintx4;

__device__ __forceinline__ uint32_t bf16rne(float f) {
  uint32_t u = __float_as_uint(f);
  return (u + 0x7FFFu + ((u >> 16) & 1u)) >> 16;
}

#define SBAR() __builtin_amdgcn_sched_barrier(0)

// ---------------------------------------------------------------------------
// R16: R15 confirmed outcome (b): the transpose access pattern is pinned at
// ~3.3 TB/s combined across SEVEN schedules (54-58.5us) -- schedule space is
// exhausted. So cut the BYTES instead: x1 has NO halo reuse in corr (each
// block reads a private 16KB tile once), so the x1 transpose round-trip
// (63 MB read + 31.5 MB write + 31.5 MB re-read) is pure overhead. R16:
//   - transpose is x2-ONLY (R15 LDS-free structure, half the traffic),
//   - corr stages x1 directly from the f32 source: 8 float4/thread in
//     16 x 64B-aligned full-line segments per wave-instr, bf16rne convert
//     (identical rounding -> bit-identical), tiny LDS [64][136] bf16 tile,
//     b128 bfrag reads; the proven SBAR afrag pipeline is untouched.
// Predicted: transpose ~29us, corr ~29us, bench ~128-140us.
// ---------------------------------------------------------------------------

// ---- transpose+convert x2 only: (B,C,H,W) f32 -> (B, C/8, HW, 8) bf16 -----
#define TPXF 1024
__global__ __launch_bounds__(256, 8)
void transpose_kernel(const float* __restrict__ x2, ushort* __restrict__ x2t) {
  const int t   = threadIdx.x;
  const int b   = blockIdx.y;
  const int px0 = blockIdx.x * TPXF;    // HW/1024 = 15 tiles
  const int cg  = blockIdx.z;           // 0..15

  const float* sb = x2 + (size_t)(b * Cc + cg * 8) * HW + px0 + t * 4;
  floatx4 v0 = *(const floatx4*)(sb + (size_t)0 * HW);
  floatx4 v1 = *(const floatx4*)(sb + (size_t)1 * HW);
  floatx4 v2 = *(const floatx4*)(sb + (size_t)2 * HW);
  floatx4 v3 = *(const floatx4*)(sb + (size_t)3 * HW);
  floatx4 v4 = *(const floatx4*)(sb + (size_t)4 * HW);
  floatx4 v5 = *(const floatx4*)(sb + (size_t)5 * HW);
  floatx4 v6 = *(const floatx4*)(sb + (size_t)6 * HW);
  floatx4 v7 = *(const floatx4*)(sb + (size_t)7 * HW);
  SBAR();

  ushort* dbase = x2t + (((size_t)b * 16 + cg) * HW + px0 + t * 4) * 8;
#pragma unroll
  for (int j = 0; j < 4; ++j) {
    uintx4 q = (uintx4){bf16rne(v0[j]) | (bf16rne(v1[j]) << 16),
                        bf16rne(v2[j]) | (bf16rne(v3[j]) << 16),
                        bf16rne(v4[j]) | (bf16rne(v5[j]) << 16),
                        bf16rne(v6[j]) | (bf16rne(v7[j]) << 16)};
    *(uintx4*)&dbase[(size_t)j * 8] = q;
  }
}

// ---- correlation: x2 from transposed bf16, x1 staged in-kernel ------------
__device__ __forceinline__ int clampi(int v, int lo, int hi) {
  return v < lo ? lo : (v > hi ? hi : v);
}

#define CKSTEP ((long)4 * HW * 8)
#define X1STR 136   // ushort stride per px row: 272B = 17*16 -> b128-aligned

#define LOADRAW(dst, tt, ckc)                                                  \
  dst = *(const short8*)&base2c[rowoff##tt + (ckc) * CKSTEP];

#define ZSEL(v, tt)                                                            \
  v = (okw && (unsigned)(gh2b + (tt)) < (unsigned)Hh) ? v                      \
      : (short8){0, 0, 0, 0, 0, 0, 0, 0};

__global__ __launch_bounds__(256, 3)
void corr_t4_kernel(const float* __restrict__ x1, const ushort* __restrict__ x2t,
                    float* __restrict__ out) {
  __shared__ float  ldsOut[Kk * 66];     // 21384 B
  __shared__ ushort ldsX1[64 * X1STR];   // 17408 B

  const int tid  = threadIdx.x;
  const int flat = blockIdx.x;
  const int b  = flat & 7;
  const int j  = flat >> 3;        // 0..239
  const int by = j / 10;           // 0..23
  const int bx = j - by * 10;      // 0..9
  const int w0 = bx * 16;
  const int h0 = by * 4;

  const int lane = tid & 63;
  const int wv   = tid >> 6;       // 0..3
  const int vy = wv & 1, vx = wv >> 1;
  const int n = lane & 15, quad = lane >> 4;
  const int s = n >> 3, pw = n & 7;

  // ---- stage x1 tile (64px x 128ch f32 -> bf16 LDS [px][c]) ----
  // 8 float4/thread; per wave-instr: 4ch x 4rows x 64B full-line segments.
  {
    const float* x1base = x1 + (size_t)(b * Cc) * HW + (size_t)h0 * Ww + w0;
#pragma unroll
    for (int it = 0; it < 8; ++it) {
      int T   = it * 256 + tid;     // 0..2047
      int c   = T >> 4;             // 0..127
      int rem = T & 15;
      int r   = rem >> 2;           // 0..3
      int q4  = rem & 3;            // 0..3
      floatx4 v = *(const floatx4*)&x1base[(size_t)c * HW + r * Ww + q4 * 4];
      int px = r * 16 + q4 * 4;
#pragma unroll
      for (int jj = 0; jj < 4; ++jj)
        ldsX1[(px + jj) * X1STR + c] = (ushort)bf16rne(v[jj]);
    }
  }

  floatx4 acc[10];
#pragma unroll
  for (int t = 0; t < 10; ++t) acc[t] = (floatx4){0.f, 0.f, 0.f, 0.f};

  const int gw2  = w0 - 4 + 8 * vx + n;
  const bool okw = (unsigned)gw2 < (unsigned)Ww;
  const int gw2c = clampi(gw2, 0, Ww - 1);
  const int gh2b = h0 - 4 + 2 * vy;

  const ushort* base2c = x2t + (((long)b * 16 + quad) * HW + gw2c) * 8;

  const long rowoff0 = (long)clampi(gh2b + 0, 0, Hh - 1) * (Ww * 8);
  const long rowoff1 = (long)clampi(gh2b + 1, 0, Hh - 1) * (Ww * 8);
  const long rowoff2 = (long)clampi(gh2b + 2, 0, Hh - 1) * (Ww * 8);
  const long rowoff3 = (long)clampi(gh2b + 3, 0, Hh - 1) * (Ww * 8);
  const long rowoff4 = (long)clampi(gh2b + 4, 0, Hh - 1) * (Ww * 8);
  const long rowoff5 = (long)clampi(gh2b + 5, 0, Hh - 1) * (Ww * 8);
  const long rowoff6 = (long)clampi(gh2b + 6, 0, Hh - 1) * (Ww * 8);
  const long rowoff7 = (long)clampi(gh2b + 7, 0, Hh - 1) * (Ww * 8);
  const long rowoff8 = (long)clampi(gh2b + 8, 0, Hh - 1) * (Ww * 8);
  const long rowoff9 = (long)clampi(gh2b + 9, 0, Hh - 1) * (Ww * 8);

  short8 aA0, aA1, aA2, aA3, aA4, aA5, aA6, aA7, aA8, aA9;
  short8 aB0, aB1, aB2, aB3, aB4, aB5, aB6, aB7, aB8, aB9;

  // issue ck=0/ck=1 afrag clusters while x1 staging drains
  LOADRAW(aA0, 0, 0); LOADRAW(aA1, 1, 0); LOADRAW(aA2, 2, 0); LOADRAW(aA3, 3, 0);
  LOADRAW(aA4, 4, 0); LOADRAW(aA5, 5, 0); LOADRAW(aA6, 6, 0); LOADRAW(aA7, 7, 0);
  LOADRAW(aA8, 8, 0); LOADRAW(aA9, 9, 0);
  SBAR();
  LOADRAW(aB0, 0, 1); LOADRAW(aB1, 1, 1); LOADRAW(aB2, 2, 1); LOADRAW(aB3, 3, 1);
  LOADRAW(aB4, 4, 1); LOADRAW(aB5, 5, 1); LOADRAW(aB6, 6, 1); LOADRAW(aB7, 7, 1);
  LOADRAW(aB8, 8, 1); LOADRAW(aB9, 9, 1);
  SBAR();

  // x1 tile ready; read the 4 bfrags from LDS (b128, 16B-aligned)
  __syncthreads();
  const int pxl = (2 * vy + s) * 16 + 8 * vx + pw;   // 0..63
  const short8 bf0 = *(const short8*)&ldsX1[pxl * X1STR +  0 + quad * 8];
  const short8 bf1 = *(const short8*)&ldsX1[pxl * X1STR + 32 + quad * 8];
  const short8 bf2 = *(const short8*)&ldsX1[pxl * X1STR + 64 + quad * 8];
  const short8 bf3 = *(const short8*)&ldsX1[pxl * X1STR + 96 + quad * 8];
  SBAR();

  ZSEL(aA0, 0); ZSEL(aA1, 1); ZSEL(aA2, 2); ZSEL(aA3, 3); ZSEL(aA4, 4);
  ZSEL(aA5, 5); ZSEL(aA6, 6); ZSEL(aA7, 7); ZSEL(aA8, 8); ZSEL(aA9, 9);
  acc[0] = __builtin_amdgcn_mfma_f32_16x16x32_bf16(aA0, bf0, acc[0], 0, 0, 0);
  acc[1] = __builtin_amdgcn_mfma_f32_16x16x32_bf16(aA1, bf0, acc[1], 0, 0, 0);
  acc[2] = __builtin_amdgcn_mfma_f32_16x16x32_bf16(aA2, bf0, acc[2], 0, 0, 0);
  acc[3] = __builtin_amdgcn_mfma_f32_16x16x32_bf16(aA3, bf0, acc[3], 0, 0, 0);
  acc[4] = __builtin_amdgcn_mfma_f32_16x16x32_bf16(aA4, bf0, acc[4], 0, 0, 0);
  acc[5] = __builtin_amdgcn_mfma_f32_16x16x32_bf16(aA5, bf0, acc[5], 0, 0, 0);
  acc[6] = __builtin_amdgcn_mfma_f32_16x16x32_bf16(aA6, bf0, acc[6], 0, 0, 0);
  acc[7] = __builtin_amdgcn_mfma_f32_16x16x32_bf16(aA7, bf0, acc[7], 0, 0, 0);
  acc[8] = __builtin_amdgcn_mfma_f32_16x16x32_bf16(aA8, bf0, acc[8], 0, 0, 0);
  acc[9] = __builtin_amdgcn_mfma_f32_16x16x32_bf16(aA9, bf0, acc[9], 0, 0, 0);
  SBAR();
  LOADRAW(aA0, 0, 2); LOADRAW(aA1, 1, 2); LOADRAW(aA2, 2, 2); LOADRAW(aA3, 3, 2);
  LOADRAW(aA4, 4, 2); LOADRAW(aA5, 5, 2); LOADRAW(aA6, 6, 2); LOADRAW(aA7, 7, 2);
  LOADRAW(aA8, 8, 2); LOADRAW(aA9, 9, 2);
  SBAR();
  ZSEL(aB0, 0); ZSEL(aB1, 1); ZSEL(aB2, 2); ZSEL(aB3, 3); ZSEL(aB4, 4);
  ZSEL(aB5, 5); ZSEL(aB6, 6); ZSEL(aB7, 7); ZSEL(aB8, 8); ZSEL(aB9, 9);
  acc[0] = __builtin_amdgcn_mfma_f32_16x16x32_bf16(aB0, bf1, acc[0], 0, 0, 0);
  acc[1] = __builtin_amdgcn_mfma_f32_16x16x32_bf16(aB1, bf1, acc[1], 0, 0, 0);
  acc[2] = __builtin_amdgcn_mfma_f32_16x16x32_bf16(aB2, bf1, acc[2], 0, 0, 0);
  acc[3] = __builtin_amdgcn_mfma_f32_16x16x32_bf16(aB3, bf1, acc[3], 0, 0, 0);
  acc[4] = __builtin_amdgcn_mfma_f32_16x16x32_bf16(aB4, bf1, acc[4], 0, 0, 0);
  acc[5] = __builtin_amdgcn_mfma_f32_16x16x32_bf16(aB5, bf1, acc[5], 0, 0, 0);
  acc[6] = __builtin_amdgcn_mfma_f32_16x16x32_bf16(aB6, bf1, acc[6], 0, 0, 0);
  acc[7] = __builtin_amdgcn_mfma_f32_16x16x32_bf16(aB7, bf1, acc[7], 0, 0, 0);
  acc[8] = __builtin_amdgcn_mfma_f32_16x16x32_bf16(aB8, bf1, acc[8], 0, 0, 0);
  acc[9] = __builtin_amdgcn_mfma_f32_16x16x32_bf16(aB9, bf1, acc[9], 0, 0, 0);
  SBAR();
  LOADRAW(aB0, 0, 3); LOADRAW(aB1, 1, 3); LOADRAW(aB2, 2, 3); LOADRAW(aB3, 3, 3);
  LOADRAW(aB4, 4, 3); LOADRAW(aB5, 5, 3); LOADRAW(aB6, 6, 3); LOADRAW(aB7, 7, 3);
  LOADRAW(aB8, 8, 3); LOADRAW(aB9, 9, 3);
  SBAR();
  ZSEL(aA0, 0); ZSEL(aA1, 1); ZSEL(aA2, 2); ZSEL(aA3, 3); ZSEL(aA4, 4);
  ZSEL(aA5, 5); ZSEL(aA6, 6); ZSEL(aA7, 7); ZSEL(aA8, 8); ZSEL(aA9, 9);
  acc[0] = __builtin_amdgcn_mfma_f32_16x16x32_bf16(aA0, bf2, acc[0], 0, 0, 0);
  acc[1] = __builtin_amdgcn_mfma_f32_16x16x32_bf16(aA1, bf2, acc[1], 0, 0, 0);
  acc[2] = __builtin_amdgcn_mfma_f32_16x16x32_bf16(aA2, bf2, acc[2], 0, 0, 0);
  acc[3] = __builtin_amdgcn_mfma_f32_16x16x32_bf16(aA3, bf2, acc[3], 0, 0, 0);
  acc[4] = __builtin_amdgcn_mfma_f32_16x16x32_bf16(aA4, bf2, acc[4], 0, 0, 0);
  acc[5] = __builtin_amdgcn_mfma_f32_16x16x32_bf16(aA5, bf2, acc[5], 0, 0, 0);
  acc[6] = __builtin_amdgcn_mfma_f32_16x16x32_bf16(aA6, bf2, acc[6], 0, 0, 0);
  acc[7] = __builtin_amdgcn_mfma_f32_16x16x32_bf16(aA7, bf2, acc[7], 0, 0, 0);
  acc[8] = __builtin_amdgcn_mfma_f32_16x16x32_bf16(aA8, bf2, acc[8], 0, 0, 0);
  acc[9] = __builtin_amdgcn_mfma_f32_16x16x32_bf16(aA9, bf2, acc[9], 0, 0, 0);
  SBAR();
  ZSEL(aB0, 0); ZSEL(aB1, 1); ZSEL(aB2, 2); ZSEL(aB3, 3); ZSEL(aB4, 4);
  ZSEL(aB5, 5); ZSEL(aB6, 6); ZSEL(aB7, 7); ZSEL(aB8, 8); ZSEL(aB9, 9);
  acc[0] = __builtin_amdgcn_mfma_f32_16x16x32_bf16(aB0, bf3, acc[0], 0, 0, 0);
  acc[1] = __builtin_amdgcn_mfma_f32_16x16x32_bf16(aB1, bf3, acc[1], 0, 0, 0);
  acc[2] = __builtin_amdgcn_mfma_f32_16x16x32_bf16(aB2, bf3, acc[2], 0, 0, 0);
  acc[3] = __builtin_amdgcn_mfma_f32_16x16x32_bf16(aB3, bf3, acc[3], 0, 0, 0);
  acc[4] = __builtin_amdgcn_mfma_f32_16x16x32_bf16(aB4, bf3, acc[4], 0, 0, 0);
  acc[5] = __builtin_amdgcn_mfma_f32_16x16x32_bf16(aB5, bf3, acc[5], 0, 0, 0);
  acc[6] = __builtin_amdgcn_mfma_f32_16x16x32_bf16(aB6, bf3, acc[6], 0, 0, 0);
  acc[7] = __builtin_amdgcn_mfma_f32_16x16x32_bf16(aB7, bf3, acc[7], 0, 0, 0);
  acc[8] = __builtin_amdgcn_mfma_f32_16x16x32_bf16(aB8, bf3, acc[8], 0, 0, 0);
  acc[9] = __builtin_amdgcn_mfma_f32_16x16x32_bf16(aB9, bf3, acc[9], 0, 0, 0);

  // ---- epilogue: scatter to padded LDS, then coalesced full-line writes ----
  const float scale = 1.0f / 128.0f;
  const int prow = 2 * vy + s;
  const int pcol = 8 * vx + pw;
#pragma unroll
  for (int t = 0; t < 10; ++t) {
    int di = t - 4 - s;
    if ((unsigned)(di + 4) > 8u) continue;
#pragma unroll
    for (int r = 0; r < 4; ++r) {
      int dj = quad * 4 + r - 4 - pw;
      if ((unsigned)(dj + 4) > 8u) continue;
      int kk = (di + 4) * 9 + (dj + 4);
      ldsOut[kk * 66 + prow * 16 + pcol] = acc[t][r] * scale;
    }
  }
  __syncthreads();

  for (int idx = tid; idx < Kk * 64; idx += 256) {
    int kk  = idx >> 6;
    int rem = idx & 63;
    int hh  = rem >> 4;
    int ww  = rem & 15;
    out[((size_t)b * Kk + kk) * HW + (size_t)(h0 + hh) * Ww + (w0 + ww)] =
        ldsOut[kk * 66 + rem];
  }
}

// ---------------------------------------------------------------------------
// R6 kernel kept verbatim as fallback when workspace is too small.
// ---------------------------------------------------------------------------
__global__ __launch_bounds__(512, 4)
void corr_kernel(const float* __restrict__ x1, const float* __restrict__ x2,
                 float* __restrict__ out) {
  __shared__ __align__(16) ushort ldsX2[16*24*40];
  __shared__ __align__(16) ushort ldsX1f[8*16*40];

  const int tid = threadIdx.x;
  const int flat = blockIdx.x;
  const int b  = flat & 7;
  const int j  = flat >> 3;
  const int by = j / 10;
  const int bx = j - by * 10;
  const int w0 = bx * 16;
  const int h0 = by * 8;

  const int lane = tid & 63;
  const int wv   = tid >> 6;
  const int vy = wv & 3, vx = wv >> 2;
  const int n = lane & 15, quad = lane >> 4;
  const int s = n >> 3, pw = n & 7;

  floatx4 acc[10];
#pragma unroll
  for (int t = 0; t < 10; ++t) acc[t] = (floatx4){0.f, 0.f, 0.f, 0.f};

  for (int ck = 0; ck < 4; ++ck) {
    const int c0 = ck * 32;
    if (ck) __syncthreads();

#pragma unroll
    for (int it = 0; it < 3; ++it) {
      int T   = it * 512 + tid;
      int w24 = T % 24;
      int t2  = T / 24;
      int rw  = t2 & 15;
      int cg  = t2 >> 4;
      int gh = h0 - 4 + rw;
      int gw = w0 - 4 + w24;
      bool ok = ((unsigned)gh < Hh) && ((unsigned)gw < Ww);
      const float* src = x2 + ((size_t)(b*Cc + c0 + cg*8) * HW + gh*Ww + gw);
      uint32_t p0, p1, p2, p3;
      {
        float a0 = ok ? src[0*HW] : 0.f;
        float a1 = ok ? src[1*HW] : 0.f;
        float a2 = ok ? src[2*HW] : 0.f;
        float a3 = ok ? src[3*HW] : 0.f;
        float a4 = ok ? src[4*HW] : 0.f;
        float a5 = ok ? src[5*HW] : 0.f;
        float a6 = ok ? src[6*HW] : 0.f;
        float a7 = ok ? src[7*HW] : 0.f;
        p0 = bf16rne(a0) | (bf16rne(a1) << 16);
        p1 = bf16rne(a2) | (bf16rne(a3) << 16);
        p2 = bf16rne(a4) | (bf16rne(a5) << 16);
        p3 = bf16rne(a6) | (bf16rne(a7) << 16);
      }
      *(uintx4*)&ldsX2[(rw*24 + w24)*40 + cg*8] = (uintx4){p0, p1, p2, p3};
    }

    {
      int T  = tid;
      int wl = T & 15;
      int t2 = T >> 4;
      int rl = t2 & 7;
      int cg = t2 >> 3;
      const float* src = x1 + ((size_t)(b*Cc + c0 + cg*8) * HW
                               + (h0 + rl)*Ww + (w0 + wl));
      uint32_t p0, p1, p2, p3;
      float a0 = src[0*HW], a1 = src[1*HW], a2 = src[2*HW], a3 = src[3*HW];
      float a4 = src[4*HW], a5 = src[5*HW], a6 = src[6*HW], a7 = src[7*HW];
      p0 = bf16rne(a0) | (bf16rne(a1) << 16);
      p1 = bf16rne(a2) | (bf16rne(a3) << 16);
      p2 = bf16rne(a4) | (bf16rne(a5) << 16);
      p3 = bf16rne(a6) | (bf16rne(a7) << 16);
      *(uintx4*)&ldsX1f[(rl*16 + wl)*40 + cg*8] = (uintx4){p0, p1, p2, p3};
    }

    __syncthreads();

    short8 bfrag = *(const short8*)&ldsX1f[((2*vy + s)*16 + 8*vx + pw)*40 + quad*8];
#pragma unroll
    for (int t = 0; t < 10; ++t) {
      short8 afrag = *(const short8*)&ldsX2[((2*vy + t)*24 + 8*vx + n)*40 + quad*8];
      acc[t] = __builtin_amdgcn_mfma_f32_16x16x32_bf16(afrag, bfrag, acc[t], 0, 0, 0);
    }
  }

  const float scale = 1.0f / 128.0f;
  const int ph  = h0 + 2*vy + s;
  const int pwg = w0 + 8*vx + pw;
#pragma unroll
  for (int t = 0; t < 10; ++t) {
    int di = t - 4 - s;
    if ((unsigned)(di + 4) > 8u) continue;
#pragma unroll
    for (int r = 0; r < 4; ++r) {
      int dj = quad*4 + r - 4 - pw;
      if ((unsigned)(dj + 4) > 8u) continue;
      int kk = (di + 4) * 9 + (dj + 4);
      out[((size_t)b*Kk + kk) * HW + ph*Ww + pwg] = acc[t][r] * scale;
    }
  }
}

extern "C" void kernel_launch(void* const* d_in, const int* in_sizes, int n_in,
                              void* d_out, int out_size, void* d_ws, size_t ws_size,
                              hipStream_t stream) {
  const float* x1 = (const float*)d_in[0];
  const float* x2 = (const float*)d_in[1];
  float* out = (float*)d_out;

  const size_t elems = (size_t)Bb * HW * Cc;              // 15,728,640
  const size_t need  = elems * sizeof(ushort);            // 31,457,280 B (x2t only)

  if (d_ws != nullptr && ws_size >= need) {
    ushort* x2t = (ushort*)d_ws;
    transpose_kernel<<<dim3(HW / TPXF, Bb, 16), dim3(256, 1, 1), 0, stream>>>(
        x2, x2t);
    corr_t4_kernel<<<dim3(1920, 1, 1), dim3(256, 1, 1), 0, stream>>>(x1, x2t, out);
  } else {
    corr_kernel<<<dim3(960, 1, 1), dim3(512, 1, 1), 0, stream>>>(x1, x2, out);
  }
}

// Round 12
// 183.034 us; speedup vs baseline: 1.0141x; 1.0141x over previous
//
#include <hip/hip_runtime.h>
#include <stdint.h>
#include <stddef.h>

#define Bb 8
#define Cc 128
#define Hh 96
#define Ww 160
#define HW (Hh*Ww)         // 15360
#define Kk 81

typedef __attribute__((ext_vector_type(8))) short short8;
typedef __attribute__((ext_vector_type(4))) float floatx4;
typedef __attribute__((ext_vector_type(4))) unsigned int uintx4;

__device__ __forceinline__ uint32_t bf16rne(float f) {
  uint32_t u = __float_as_uint(f);
  return (u + 0x7FFFu + ((u >> 16) & 1u)) >> 16;
}

#define SBAR() __builtin_amdgcn_sched_barrier(0)

// ---------------------------------------------------------------------------
// R17: R16 post-mortem -- transpose halved on schedule (~28us), but corr_t4
// regressed 24->50us from staging MECHANICS, not the gather itself:
// 32 scalar ushort LDS stores/thread at 8-way conflict (4.05M conflict
// cycles), 32 scalar converts, and staging loads serial in front of the
// MFMA pipeline. R17 fixes the mechanics, keeps the structure:
//  1) in-register 8-channel pack (R15 trick): 8 float4 loads -> 4 b128 LDS
//     stores per thread (was 32 scalar).
//  2) T14 async split: staging loads issued FIRST, then the 20 afrag loads,
//     THEN pack (counted vmcnt -- staging latency hides under afrag issue).
//  3) ldsX1 unioned with ldsOut (dead after bfrag reads): LDS 39->21.5KB.
// Predicted: corr ~38-43us, bench ~152-165. If corr >= 46us with conflicts
// fixed -> gather is byte-wall-pinned -> revert/declare next round.
// ---------------------------------------------------------------------------

// ---- transpose+convert x2 only: (B,C,H,W) f32 -> (B, C/8, HW, 8) bf16 -----
#define TPXF 1024
__global__ __launch_bounds__(256, 8)
void transpose_kernel(const float* __restrict__ x2, ushort* __restrict__ x2t) {
  const int t   = threadIdx.x;
  const int b   = blockIdx.y;
  const int px0 = blockIdx.x * TPXF;    // HW/1024 = 15 tiles
  const int cg  = blockIdx.z;           // 0..15

  const float* sb = x2 + (size_t)(b * Cc + cg * 8) * HW + px0 + t * 4;
  floatx4 v0 = *(const floatx4*)(sb + (size_t)0 * HW);
  floatx4 v1 = *(const floatx4*)(sb + (size_t)1 * HW);
  floatx4 v2 = *(const floatx4*)(sb + (size_t)2 * HW);
  floatx4 v3 = *(const floatx4*)(sb + (size_t)3 * HW);
  floatx4 v4 = *(const floatx4*)(sb + (size_t)4 * HW);
  floatx4 v5 = *(const floatx4*)(sb + (size_t)5 * HW);
  floatx4 v6 = *(const floatx4*)(sb + (size_t)6 * HW);
  floatx4 v7 = *(const floatx4*)(sb + (size_t)7 * HW);
  SBAR();

  ushort* dbase = x2t + (((size_t)b * 16 + cg) * HW + px0 + t * 4) * 8;
#pragma unroll
  for (int j = 0; j < 4; ++j) {
    uintx4 q = (uintx4){bf16rne(v0[j]) | (bf16rne(v1[j]) << 16),
                        bf16rne(v2[j]) | (bf16rne(v3[j]) << 16),
                        bf16rne(v4[j]) | (bf16rne(v5[j]) << 16),
                        bf16rne(v6[j]) | (bf16rne(v7[j]) << 16)};
    *(uintx4*)&dbase[(size_t)j * 8] = q;
  }
}

// ---- correlation: x2 from transposed bf16, x1 packed-staged in-kernel -----
__device__ __forceinline__ int clampi(int v, int lo, int hi) {
  return v < lo ? lo : (v > hi ? hi : v);
}

#define CKSTEP ((long)4 * HW * 8)
#define X1STR 136   // ushort stride per px row: 272B, b128-aligned

#define LOADRAW(dst, tt, ckc)                                                  \
  dst = *(const short8*)&base2c[rowoff##tt + (ckc) * CKSTEP];

#define ZSEL(v, tt)                                                            \
  v = (okw && (unsigned)(gh2b + (tt)) < (unsigned)Hh) ? v                      \
      : (short8){0, 0, 0, 0, 0, 0, 0, 0};

__global__ __launch_bounds__(256, 3)
void corr_t5_kernel(const float* __restrict__ x1, const ushort* __restrict__ x2t,
                    float* __restrict__ out) {
  // union: ldsX1 (17408B) lives only until bfrag reads; ldsOut (21384B) after.
  __shared__ __align__(16) unsigned char ldsRaw[Kk * 66 * 4];   // 21384 B
  ushort* ldsX1  = (ushort*)ldsRaw;
  float*  ldsOut = (float*)ldsRaw;

  const int tid  = threadIdx.x;
  const int flat = blockIdx.x;
  const int b  = flat & 7;
  const int j  = flat >> 3;        // 0..239
  const int by = j / 10;           // 0..23
  const int bx = j - by * 10;      // 0..9
  const int w0 = bx * 16;
  const int h0 = by * 4;

  const int lane = tid & 63;
  const int wv   = tid >> 6;       // 0..3
  const int vy = wv & 1, vx = wv >> 1;
  const int n = lane & 15, quad = lane >> 4;
  const int s = n >> 3, pw = n & 7;

  // ---- (1) issue x1 staging loads FIRST (8 float4: 4px x 8ch per thread) --
  const int p   = tid & 15;        // px-quad id: row rs, w-offset ws4
  const int cgs = tid >> 4;        // 0..15 channel group
  const int rs  = p >> 2;
  const int ws4 = (p & 3) * 4;
  const float* x1b = x1 + (size_t)(b * Cc + cgs * 8) * HW
                        + (size_t)(h0 + rs) * Ww + w0 + ws4;
  floatx4 u0 = *(const floatx4*)(x1b + (size_t)0 * HW);
  floatx4 u1 = *(const floatx4*)(x1b + (size_t)1 * HW);
  floatx4 u2 = *(const floatx4*)(x1b + (size_t)2 * HW);
  floatx4 u3 = *(const floatx4*)(x1b + (size_t)3 * HW);
  floatx4 u4 = *(const floatx4*)(x1b + (size_t)4 * HW);
  floatx4 u5 = *(const floatx4*)(x1b + (size_t)5 * HW);
  floatx4 u6 = *(const floatx4*)(x1b + (size_t)6 * HW);
  floatx4 u7 = *(const floatx4*)(x1b + (size_t)7 * HW);
  SBAR();

  // ---- (2) issue both afrag clusters (x2t, clean 256B segments) ----
  const int gw2  = w0 - 4 + 8 * vx + n;
  const bool okw = (unsigned)gw2 < (unsigned)Ww;
  const int gw2c = clampi(gw2, 0, Ww - 1);
  const int gh2b = h0 - 4 + 2 * vy;

  const ushort* base2c = x2t + (((long)b * 16 + quad) * HW + gw2c) * 8;

  const long rowoff0 = (long)clampi(gh2b + 0, 0, Hh - 1) * (Ww * 8);
  const long rowoff1 = (long)clampi(gh2b + 1, 0, Hh - 1) * (Ww * 8);
  const long rowoff2 = (long)clampi(gh2b + 2, 0, Hh - 1) * (Ww * 8);
  const long rowoff3 = (long)clampi(gh2b + 3, 0, Hh - 1) * (Ww * 8);
  const long rowoff4 = (long)clampi(gh2b + 4, 0, Hh - 1) * (Ww * 8);
  const long rowoff5 = (long)clampi(gh2b + 5, 0, Hh - 1) * (Ww * 8);
  const long rowoff6 = (long)clampi(gh2b + 6, 0, Hh - 1) * (Ww * 8);
  const long rowoff7 = (long)clampi(gh2b + 7, 0, Hh - 1) * (Ww * 8);
  const long rowoff8 = (long)clampi(gh2b + 8, 0, Hh - 1) * (Ww * 8);
  const long rowoff9 = (long)clampi(gh2b + 9, 0, Hh - 1) * (Ww * 8);

  short8 aA0, aA1, aA2, aA3, aA4, aA5, aA6, aA7, aA8, aA9;
  short8 aB0, aB1, aB2, aB3, aB4, aB5, aB6, aB7, aB8, aB9;

  LOADRAW(aA0, 0, 0); LOADRAW(aA1, 1, 0); LOADRAW(aA2, 2, 0); LOADRAW(aA3, 3, 0);
  LOADRAW(aA4, 4, 0); LOADRAW(aA5, 5, 0); LOADRAW(aA6, 6, 0); LOADRAW(aA7, 7, 0);
  LOADRAW(aA8, 8, 0); LOADRAW(aA9, 9, 0);
  SBAR();
  LOADRAW(aB0, 0, 1); LOADRAW(aB1, 1, 1); LOADRAW(aB2, 2, 1); LOADRAW(aB3, 3, 1);
  LOADRAW(aB4, 4, 1); LOADRAW(aB5, 5, 1); LOADRAW(aB6, 6, 1); LOADRAW(aB7, 7, 1);
  LOADRAW(aB8, 8, 1); LOADRAW(aB9, 9, 1);
  SBAR();

  // ---- (3) pack + 4 b128 LDS writes (waits staging loads only) ----
  {
    const int pxb = rs * 16 + ws4;
#pragma unroll
    for (int jj = 0; jj < 4; ++jj) {
      uintx4 q = (uintx4){bf16rne(u0[jj]) | (bf16rne(u1[jj]) << 16),
                          bf16rne(u2[jj]) | (bf16rne(u3[jj]) << 16),
                          bf16rne(u4[jj]) | (bf16rne(u5[jj]) << 16),
                          bf16rne(u6[jj]) | (bf16rne(u7[jj]) << 16)};
      *(uintx4*)&ldsX1[(pxb + jj) * X1STR + cgs * 8] = q;
    }
  }
  __syncthreads();

  // ---- bfrag reads (b128), then barrier so ldsOut can reuse the buffer ----
  const int pxl = (2 * vy + s) * 16 + 8 * vx + pw;   // 0..63
  const short8 bf0 = *(const short8*)&ldsX1[pxl * X1STR +  0 + quad * 8];
  const short8 bf1 = *(const short8*)&ldsX1[pxl * X1STR + 32 + quad * 8];
  const short8 bf2 = *(const short8*)&ldsX1[pxl * X1STR + 64 + quad * 8];
  const short8 bf3 = *(const short8*)&ldsX1[pxl * X1STR + 96 + quad * 8];
  __syncthreads();
  SBAR();

  floatx4 acc[10];
#pragma unroll
  for (int t = 0; t < 10; ++t) acc[t] = (floatx4){0.f, 0.f, 0.f, 0.f};

  ZSEL(aA0, 0); ZSEL(aA1, 1); ZSEL(aA2, 2); ZSEL(aA3, 3); ZSEL(aA4, 4);
  ZSEL(aA5, 5); ZSEL(aA6, 6); ZSEL(aA7, 7); ZSEL(aA8, 8); ZSEL(aA9, 9);
  acc[0] = __builtin_amdgcn_mfma_f32_16x16x32_bf16(aA0, bf0, acc[0], 0, 0, 0);
  acc[1] = __builtin_amdgcn_mfma_f32_16x16x32_bf16(aA1, bf0, acc[1], 0, 0, 0);
  acc[2] = __builtin_amdgcn_mfma_f32_16x16x32_bf16(aA2, bf0, acc[2], 0, 0, 0);
  acc[3] = __builtin_amdgcn_mfma_f32_16x16x32_bf16(aA3, bf0, acc[3], 0, 0, 0);
  acc[4] = __builtin_amdgcn_mfma_f32_16x16x32_bf16(aA4, bf0, acc[4], 0, 0, 0);
  acc[5] = __builtin_amdgcn_mfma_f32_16x16x32_bf16(aA5, bf0, acc[5], 0, 0, 0);
  acc[6] = __builtin_amdgcn_mfma_f32_16x16x32_bf16(aA6, bf0, acc[6], 0, 0, 0);
  acc[7] = __builtin_amdgcn_mfma_f32_16x16x32_bf16(aA7, bf0, acc[7], 0, 0, 0);
  acc[8] = __builtin_amdgcn_mfma_f32_16x16x32_bf16(aA8, bf0, acc[8], 0, 0, 0);
  acc[9] = __builtin_amdgcn_mfma_f32_16x16x32_bf16(aA9, bf0, acc[9], 0, 0, 0);
  SBAR();
  LOADRAW(aA0, 0, 2); LOADRAW(aA1, 1, 2); LOADRAW(aA2, 2, 2); LOADRAW(aA3, 3, 2);
  LOADRAW(aA4, 4, 2); LOADRAW(aA5, 5, 2); LOADRAW(aA6, 6, 2); LOADRAW(aA7, 7, 2);
  LOADRAW(aA8, 8, 2); LOADRAW(aA9, 9, 2);
  SBAR();
  ZSEL(aB0, 0); ZSEL(aB1, 1); ZSEL(aB2, 2); ZSEL(aB3, 3); ZSEL(aB4, 4);
  ZSEL(aB5, 5); ZSEL(aB6, 6); ZSEL(aB7, 7); ZSEL(aB8, 8); ZSEL(aB9, 9);
  acc[0] = __builtin_amdgcn_mfma_f32_16x16x32_bf16(aB0, bf1, acc[0], 0, 0, 0);
  acc[1] = __builtin_amdgcn_mfma_f32_16x16x32_bf16(aB1, bf1, acc[1], 0, 0, 0);
  acc[2] = __builtin_amdgcn_mfma_f32_16x16x32_bf16(aB2, bf1, acc[2], 0, 0, 0);
  acc[3] = __builtin_amdgcn_mfma_f32_16x16x32_bf16(aB3, bf1, acc[3], 0, 0, 0);
  acc[4] = __builtin_amdgcn_mfma_f32_16x16x32_bf16(aB4, bf1, acc[4], 0, 0, 0);
  acc[5] = __builtin_amdgcn_mfma_f32_16x16x32_bf16(aB5, bf1, acc[5], 0, 0, 0);
  acc[6] = __builtin_amdgcn_mfma_f32_16x16x32_bf16(aB6, bf1, acc[6], 0, 0, 0);
  acc[7] = __builtin_amdgcn_mfma_f32_16x16x32_bf16(aB7, bf1, acc[7], 0, 0, 0);
  acc[8] = __builtin_amdgcn_mfma_f32_16x16x32_bf16(aB8, bf1, acc[8], 0, 0, 0);
  acc[9] = __builtin_amdgcn_mfma_f32_16x16x32_bf16(aB9, bf1, acc[9], 0, 0, 0);
  SBAR();
  LOADRAW(aB0, 0, 3); LOADRAW(aB1, 1, 3); LOADRAW(aB2, 2, 3); LOADRAW(aB3, 3, 3);
  LOADRAW(aB4, 4, 3); LOADRAW(aB5, 5, 3); LOADRAW(aB6, 6, 3); LOADRAW(aB7, 7, 3);
  LOADRAW(aB8, 8, 3); LOADRAW(aB9, 9, 3);
  SBAR();
  ZSEL(aA0, 0); ZSEL(aA1, 1); ZSEL(aA2, 2); ZSEL(aA3, 3); ZSEL(aA4, 4);
  ZSEL(aA5, 5); ZSEL(aA6, 6); ZSEL(aA7, 7); ZSEL(aA8, 8); ZSEL(aA9, 9);
  acc[0] = __builtin_amdgcn_mfma_f32_16x16x32_bf16(aA0, bf2, acc[0], 0, 0, 0);
  acc[1] = __builtin_amdgcn_mfma_f32_16x16x32_bf16(aA1, bf2, acc[1], 0, 0, 0);
  acc[2] = __builtin_amdgcn_mfma_f32_16x16x32_bf16(aA2, bf2, acc[2], 0, 0, 0);
  acc[3] = __builtin_amdgcn_mfma_f32_16x16x32_bf16(aA3, bf2, acc[3], 0, 0, 0);
  acc[4] = __builtin_amdgcn_mfma_f32_16x16x32_bf16(aA4, bf2, acc[4], 0, 0, 0);
  acc[5] = __builtin_amdgcn_mfma_f32_16x16x32_bf16(aA5, bf2, acc[5], 0, 0, 0);
  acc[6] = __builtin_amdgcn_mfma_f32_16x16x32_bf16(aA6, bf2, acc[6], 0, 0, 0);
  acc[7] = __builtin_amdgcn_mfma_f32_16x16x32_bf16(aA7, bf2, acc[7], 0, 0, 0);
  acc[8] = __builtin_amdgcn_mfma_f32_16x16x32_bf16(aA8, bf2, acc[8], 0, 0, 0);
  acc[9] = __builtin_amdgcn_mfma_f32_16x16x32_bf16(aA9, bf2, acc[9], 0, 0, 0);
  SBAR();
  ZSEL(aB0, 0); ZSEL(aB1, 1); ZSEL(aB2, 2); ZSEL(aB3, 3); ZSEL(aB4, 4);
  ZSEL(aB5, 5); ZSEL(aB6, 6); ZSEL(aB7, 7); ZSEL(aB8, 8); ZSEL(aB9, 9);
  acc[0] = __builtin_amdgcn_mfma_f32_16x16x32_bf16(aB0, bf3, acc[0], 0, 0, 0);
  acc[1] = __builtin_amdgcn_mfma_f32_16x16x32_bf16(aB1, bf3, acc[1], 0, 0, 0);
  acc[2] = __builtin_amdgcn_mfma_f32_16x16x32_bf16(aB2, bf3, acc[2], 0, 0, 0);
  acc[3] = __builtin_amdgcn_mfma_f32_16x16x32_bf16(aB3, bf3, acc[3], 0, 0, 0);
  acc[4] = __builtin_amdgcn_mfma_f32_16x16x32_bf16(aB4, bf3, acc[4], 0, 0, 0);
  acc[5] = __builtin_amdgcn_mfma_f32_16x16x32_bf16(aB5, bf3, acc[5], 0, 0, 0);
  acc[6] = __builtin_amdgcn_mfma_f32_16x16x32_bf16(aB6, bf3, acc[6], 0, 0, 0);
  acc[7] = __builtin_amdgcn_mfma_f32_16x16x32_bf16(aB7, bf3, acc[7], 0, 0, 0);
  acc[8] = __builtin_amdgcn_mfma_f32_16x16x32_bf16(aB8, bf3, acc[8], 0, 0, 0);
  acc[9] = __builtin_amdgcn_mfma_f32_16x16x32_bf16(aB9, bf3, acc[9], 0, 0, 0);

  // ---- epilogue: scatter to ldsOut (reused buffer), coalesced writes ----
  const float scale = 1.0f / 128.0f;
  const int prow = 2 * vy + s;
  const int pcol = 8 * vx + pw;
#pragma unroll
  for (int t = 0; t < 10; ++t) {
    int di = t - 4 - s;
    if ((unsigned)(di + 4) > 8u) continue;
#pragma unroll
    for (int r = 0; r < 4; ++r) {
      int dj = quad * 4 + r - 4 - pw;
      if ((unsigned)(dj + 4) > 8u) continue;
      int kk = (di + 4) * 9 + (dj + 4);
      ldsOut[kk * 66 + prow * 16 + pcol] = acc[t][r] * scale;
    }
  }
  __syncthreads();

  for (int idx = tid; idx < Kk * 64; idx += 256) {
    int kk  = idx >> 6;
    int rem = idx & 63;
    int hh  = rem >> 4;
    int ww  = rem & 15;
    out[((size_t)b * Kk + kk) * HW + (size_t)(h0 + hh) * Ww + (w0 + ww)] =
        ldsOut[kk * 66 + rem];
  }
}

// ---------------------------------------------------------------------------
// R6 kernel kept verbatim as fallback when workspace is too small.
// ---------------------------------------------------------------------------
__global__ __launch_bounds__(512, 4)
void corr_kernel(const float* __restrict__ x1, const float* __restrict__ x2,
                 float* __restrict__ out) {
  __shared__ __align__(16) ushort ldsX2[16*24*40];
  __shared__ __align__(16) ushort ldsX1f[8*16*40];

  const int tid = threadIdx.x;
  const int flat = blockIdx.x;
  const int b  = flat & 7;
  const int j  = flat >> 3;
  const int by = j / 10;
  const int bx = j - by * 10;
  const int w0 = bx * 16;
  const int h0 = by * 8;

  const int lane = tid & 63;
  const int wv   = tid >> 6;
  const int vy = wv & 3, vx = wv >> 2;
  const int n = lane & 15, quad = lane >> 4;
  const int s = n >> 3, pw = n & 7;

  floatx4 acc[10];
#pragma unroll
  for (int t = 0; t < 10; ++t) acc[t] = (floatx4){0.f, 0.f, 0.f, 0.f};

  for (int ck = 0; ck < 4; ++ck) {
    const int c0 = ck * 32;
    if (ck) __syncthreads();

#pragma unroll
    for (int it = 0; it < 3; ++it) {
      int T   = it * 512 + tid;
      int w24 = T % 24;
      int t2  = T / 24;
      int rw  = t2 & 15;
      int cg  = t2 >> 4;
      int gh = h0 - 4 + rw;
      int gw = w0 - 4 + w24;
      bool ok = ((unsigned)gh < Hh) && ((unsigned)gw < Ww);
      const float* src = x2 + ((size_t)(b*Cc + c0 + cg*8) * HW + gh*Ww + gw);
      uint32_t p0, p1, p2, p3;
      {
        float a0 = ok ? src[0*HW] : 0.f;
        float a1 = ok ? src[1*HW] : 0.f;
        float a2 = ok ? src[2*HW] : 0.f;
        float a3 = ok ? src[3*HW] : 0.f;
        float a4 = ok ? src[4*HW] : 0.f;
        float a5 = ok ? src[5*HW] : 0.f;
        float a6 = ok ? src[6*HW] : 0.f;
        float a7 = ok ? src[7*HW] : 0.f;
        p0 = bf16rne(a0) | (bf16rne(a1) << 16);
        p1 = bf16rne(a2) | (bf16rne(a3) << 16);
        p2 = bf16rne(a4) | (bf16rne(a5) << 16);
        p3 = bf16rne(a6) | (bf16rne(a7) << 16);
      }
      *(uintx4*)&ldsX2[(rw*24 + w24)*40 + cg*8] = (uintx4){p0, p1, p2, p3};
    }

    {
      int T  = tid;
      int wl = T & 15;
      int t2 = T >> 4;
      int rl = t2 & 7;
      int cg = t2 >> 3;
      const float* src = x1 + ((size_t)(b*Cc + c0 + cg*8) * HW
                               + (h0 + rl)*Ww + (w0 + wl));
      uint32_t p0, p1, p2, p3;
      float a0 = src[0*HW], a1 = src[1*HW], a2 = src[2*HW], a3 = src[3*HW];
      float a4 = src[4*HW], a5 = src[5*HW], a6 = src[6*HW], a7 = src[7*HW];
      p0 = bf16rne(a0) | (bf16rne(a1) << 16);
      p1 = bf16rne(a2) | (bf16rne(a3) << 16);
      p2 = bf16rne(a4) | (bf16rne(a5) << 16);
      p3 = bf16rne(a6) | (bf16rne(a7) << 16);
      *(uintx4*)&ldsX1f[(rl*16 + wl)*40 + cg*8] = (uintx4){p0, p1, p2, p3};
    }

    __syncthreads();

    short8 bfrag = *(const short8*)&ldsX1f[((2*vy + s)*16 + 8*vx + pw)*40 + quad*8];
#pragma unroll
    for (int t = 0; t < 10; ++t) {
      short8 afrag = *(const short8*)&ldsX2[((2*vy + t)*24 + 8*vx + n)*40 + quad*8];
      acc[t] = __builtin_amdgcn_mfma_f32_16x16x32_bf16(afrag, bfrag, acc[t], 0, 0, 0);
    }
  }

  const float scale = 1.0f / 128.0f;
  const int ph  = h0 + 2*vy + s;
  const int pwg = w0 + 8*vx + pw;
#pragma unroll
  for (int t = 0; t < 10; ++t) {
    int di = t - 4 - s;
    if ((unsigned)(di + 4) > 8u) continue;
#pragma unroll
    for (int r = 0; r < 4; ++r) {
      int dj = quad*4 + r - 4 - pw;
      if ((unsigned)(dj + 4) > 8u) continue;
      int kk = (di + 4) * 9 + (dj + 4);
      out[((size_t)b*Kk + kk) * HW + ph*Ww + pwg] = acc[t][r] * scale;
    }
  }
}

extern "C" void kernel_launch(void* const* d_in, const int* in_sizes, int n_in,
                              void* d_out, int out_size, void* d_ws, size_t ws_size,
                              hipStream_t stream) {
  const float* x1 = (const float*)d_in[0];
  const float* x2 = (const float*)d_in[1];
  float* out = (float*)d_out;

  const size_t elems = (size_t)Bb * HW * Cc;              // 15,728,640
  const size_t need  = elems * sizeof(ushort);            // 31,457,280 B (x2t only)

  if (d_ws != nullptr && ws_size >= need) {
    ushort* x2t = (ushort*)d_ws;
    transpose_kernel<<<dim3(HW / TPXF, Bb, 16), dim3(256, 1, 1), 0, stream>>>(
        x2, x2t);
    corr_t5_kernel<<<dim3(1920, 1, 1), dim3(256, 1, 1), 0, stream>>>(x1, x2t, out);
  } else {
    corr_kernel<<<dim3(960, 1, 1), dim3(512, 1, 1), 0, stream>>>(x1, x2, out);
  }
}